// Round 14
// baseline (46.473 us; speedup 1.0000x reference)
//
#include <hip/hip_runtime.h>
#include <hip/hip_fp16.h>

#define DX 160
#define DY 192
#define DZ 160
#define PLANE (DY*DZ)
#define NVOX (DX*DY*DZ)

#define XC   10               // interior x slices per wave
#define NXB  (DX/XC)          // 16
#define NS   (XC+4)           // 14
#define WPB  4                // waves (= y rows) per block
#define NT   (WPB*64)         // 256 threads
#define NYB  (DY/WPB)         // 48
#define NPART (NXB*NYB*WPB)   // 3072 per-wave partials

__device__ __forceinline__ int iclamp(int v, int hi) {
    return v < 0 ? 0 : (v > hi ? hi : v);
}
__device__ __forceinline__ unsigned pk(float a, float b) {
    return __builtin_bit_cast(unsigned, __floats2half2_rn(a, b));
}
__device__ __forceinline__ float lo16(unsigned u) {
    return __low2float(__builtin_bit_cast(__half2, u));
}
__device__ __forceinline__ float hi16(unsigned u) {
    return __high2float(__builtin_bit_cast(__half2, u));
}

// ---------------------------------------------------------------------------
// Wave-autonomous fused LCC: ZERO LDS, ZERO barriers in the main loop.
// R5-R13 invariants: all pipes <25%, occupancy pinned ~25%, time ~ slice
// count, for EVERY barrier/grid/pipeline variant -> the block-wide barrier +
// cross-wave LDS handoff is itself the serializer. This kernel removes it:
//   - wave = one y row; lane owns z-triple (3l..3l+2), 54 lanes cover z.
//   - y-box: 5 tap rows straight from global (float4; L1 serves 5x reuse).
//   - z-box: fp16-packed neighbor exchange via 2 shuffles/quantity (wave-
//     local ds_bpermute, no sync). Edge clamps: lane0 override; lane>=53
//     duplicates its z=159 value so lane52's right taps clamp for free.
//   - x-box: proven register running window (fp16 history).
//   - reduction: wave shuffle; one partial per wave.
// 3072 independent waves (12/CU), VGPR-capped 128 -> 16 waves/CU resident.
// ---------------------------------------------------------------------------
__global__ __launch_bounds__(NT, 4) void lcc_fused(const float* __restrict__ F,
                                                   const float* __restrict__ M,
                                                   float* __restrict__ partials) {
    const int tid  = threadIdx.x;
    const int lane = tid & 63;
    const int wid  = tid >> 6;
    const int y    = blockIdx.y * WPB + wid;
    const int x0   = blockIdx.x * XC;

    // z-triple base; cap at 156 so the float4 read never leaves the row
    const int  z3   = 3 * lane;
    const int  zoff = z3 < DZ - 4 ? z3 : DZ - 4;   // <=156
    const bool hiL  = (z3 > DZ - 4);               // lanes >= 53: use v.w (z=159)

    // validity masks for the 3 z-slots
    const float mz0 = (z3 + 0 < DZ) ? 1.f : 0.f;
    const float mz1 = (z3 + 1 < DZ) ? 1.f : 0.f;
    const float mz2 = (z3 + 2 < DZ) ? 1.f : 0.f;

    int rowoff[5];
    #pragma unroll
    for (int k = 0; k < 5; ++k)
        rowoff[k] = iclamp(y + k - 2, DY - 1) * DZ + zoff;

    // x running-window state
    float    s[5][3];
    unsigned h01[4][5];   // history: fp16x2 (S[q][0], S[q][1]) per age
    float    h2v[4][5];   // history: S[q][2] (f32)
    #pragma unroll
    for (int q = 0; q < 5; ++q) { s[q][0] = 0.f; s[q][1] = 0.f; s[q][2] = 0.f; }
    #pragma unroll
    for (int a = 0; a < 4; ++a)
        #pragma unroll
        for (int q = 0; q < 5; ++q) { h01[a][q] = 0u; h2v[a][q] = 0.f; }

    float acc = 0.f;

    #pragma unroll
    for (int i = 0; i < NS; ++i) {
        const int xx = iclamp(x0 + i - 2, DX - 1);
        const float* fp = F + (size_t)xx * PLANE;
        const float* mp = M + (size_t)xx * PLANE;

        // ---- y-box over 5 tap rows, straight from global (f32 exact) ----
        float q0[5] = {0,0,0,0,0};   // quantities at z-slot 0: f,m,fm,ff,mm
        float q1[5] = {0,0,0,0,0};   // z-slot 1
        float q2[5] = {0,0,0,0,0};   // z-slot 2
        #pragma unroll
        for (int r = 0; r < 5; ++r) {
            const float4 vf = *(const float4*)(fp + rowoff[r]);
            const float4 vm = *(const float4*)(mp + rowoff[r]);
            const float f0 = hiL ? vf.w : vf.x, m0 = hiL ? vm.w : vm.x;
            const float f1 = hiL ? vf.w : vf.y, m1 = hiL ? vm.w : vm.y;
            const float f2 = hiL ? vf.w : vf.z, m2 = hiL ? vm.w : vm.z;
            q0[0] += f0; q0[1] += m0;
            q0[2] = fmaf(f0, m0, q0[2]); q0[3] = fmaf(f0, f0, q0[3]); q0[4] = fmaf(m0, m0, q0[4]);
            q1[0] += f1; q1[1] += m1;
            q1[2] = fmaf(f1, m1, q1[2]); q1[3] = fmaf(f1, f1, q1[3]); q1[4] = fmaf(m1, m1, q1[4]);
            q2[0] += f2; q2[1] += m2;
            q2[2] = fmaf(f2, m2, q2[2]); q2[3] = fmaf(f2, f2, q2[3]); q2[4] = fmaf(m2, m2, q2[4]);
        }

        // ---- z-box via wave-local shuffles (fp16 neighbor taps) ----
        float S[5][3];
        #pragma unroll
        for (int q = 0; q < 5; ++q) {
            const unsigned up = pk(q1[q], q2[q]);   // my (z1,z2) -> right neighbor
            const unsigned dn = pk(q0[q], q1[q]);   // my (z0,z1) -> left neighbor
            unsigned fl = __shfl_up(up, 1, 64);     // lane-1's (z1,z2) = my z0-2, z0-1
            unsigned fr = __shfl_down(dn, 1, 64);   // lane+1's (z0,z1) = my z2+1, z2+2
            if (lane == 0) fl = pk(q0[q], q0[q]);   // replicate pad at z=0
            // (right edge: lane>=53 duplicated z159 into q1/q2, so lane52's
            //  fr.hi == clamp(z=160) automatically; lane53 uses only S[.][0].)
            const float c = q0[q] + q1[q] + q2[q];
            S[q][0] = c + lo16(fl) + hi16(fl);
            S[q][1] = c + hi16(fl) + lo16(fr);
            S[q][2] = c + lo16(fr) + hi16(fr);
        }

        // ---- x running window + LCC ----
        #pragma unroll
        for (int q = 0; q < 5; ++q) {
            s[q][0] += S[q][0]; s[q][1] += S[q][1]; s[q][2] += S[q][2];
        }
        if (i >= 4) {
            const float inv = 1.0f / 125.0f;
            const float mz[3] = {mz0, mz1, mz2};
            #pragma unroll
            for (int j = 0; j < 3; ++j) {
                const float cross = s[2][j] - s[0][j] * s[1][j] * inv;
                const float fvar  = s[3][j] - s[0][j] * s[0][j] * inv;
                const float mvar  = s[4][j] - s[1][j] * s[1][j] * inv;
                acc += mz[j] * (cross * cross / (fvar * mvar + 0.1f));
            }
            #pragma unroll
            for (int q = 0; q < 5; ++q) {
                s[q][0] -= lo16(h01[0][q]);
                s[q][1] -= hi16(h01[0][q]);
                s[q][2] -= h2v[0][q];
            }
        }
        #pragma unroll
        for (int a = 0; a < 3; ++a)
            #pragma unroll
            for (int q = 0; q < 5; ++q) { h01[a][q] = h01[a + 1][q]; h2v[a][q] = h2v[a + 1][q]; }
        #pragma unroll
        for (int q = 0; q < 5; ++q) { h01[3][q] = pk(S[q][0], S[q][1]); h2v[3][q] = S[q][2]; }
    }

    // ---- wave reduction; one partial per wave; no LDS, no barrier ----
    #pragma unroll
    for (int off = 32; off > 0; off >>= 1) acc += __shfl_down(acc, off, 64);
    if (lane == 0)
        partials[(blockIdx.y * NXB + blockIdx.x) * WPB + wid] = acc;
}

// ---------------------------------------------------------------------------
// Final deterministic reduction, writes -sum.
// ---------------------------------------------------------------------------
__global__ __launch_bounds__(256) void lcc_finalize(const float* __restrict__ partials,
                                                    int n, float* __restrict__ out) {
    __shared__ float red[256];
    float a = 0.f;
    for (int i = threadIdx.x; i < n; i += 256) a += partials[i];
    red[threadIdx.x] = a;
    __syncthreads();
    #pragma unroll
    for (int st = 128; st > 0; st >>= 1) {
        if (threadIdx.x < st) red[threadIdx.x] += red[threadIdx.x + st];
        __syncthreads();
    }
    if (threadIdx.x == 0) out[0] = -red[0];
}

// ---------------------------------------------------------------------------
// Fallback: direct 125-tap (only if ws is tiny).
// ---------------------------------------------------------------------------
__global__ __launch_bounds__(256) void lcc_direct(const float* __restrict__ f,
                                                  const float* __restrict__ m,
                                                  float* __restrict__ partials) {
    float acc = 0.f;
    for (int idx = blockIdx.x * 256 + threadIdx.x; idx < NVOX; idx += 256 * gridDim.x) {
        const int z = idx % DZ;
        const int y = (idx / DZ) % DY;
        const int x = idx / PLANE;
        float sf = 0, sm = 0, sfm = 0, sff = 0, smm = 0;
        for (int dx = -2; dx <= 2; ++dx) {
            const int xx = iclamp(x + dx, DX - 1);
            for (int dy = -2; dy <= 2; ++dy) {
                const int yy = iclamp(y + dy, DY - 1);
                const size_t b = (size_t)xx * PLANE + (size_t)yy * DZ;
                #pragma unroll
                for (int dz = -2; dz <= 2; ++dz) {
                    const int zz = iclamp(z + dz, DZ - 1);
                    const float fv = f[b + zz], mv = m[b + zz];
                    sf += fv; sm += mv; sfm += fv * mv; sff += fv * fv; smm += mv * mv;
                }
            }
        }
        const float inv = 1.0f / 125.0f;
        const float cross = sfm - sf * sm * inv;
        const float fvar  = sff - sf * sf * inv;
        const float mvar  = smm - sm * sm * inv;
        acc += cross * cross / (fvar * mvar + 0.1f);
    }
    __shared__ float red[256];
    red[threadIdx.x] = acc;
    __syncthreads();
    #pragma unroll
    for (int st = 128; st > 0; st >>= 1) {
        if (threadIdx.x < st) red[threadIdx.x] += red[threadIdx.x + st];
        __syncthreads();
    }
    if (threadIdx.x == 0) partials[blockIdx.x] = red[0];
}

extern "C" void kernel_launch(void* const* d_in, const int* in_sizes, int n_in,
                              void* d_out, int out_size, void* d_ws, size_t ws_size,
                              hipStream_t stream) {
    const float* f = (const float*)d_in[0];
    const float* m = (const float*)d_in[1];
    float* out = (float*)d_out;

    if (ws_size >= NPART * sizeof(float)) {
        float* partials = (float*)d_ws;
        lcc_fused<<<dim3(NXB, NYB), NT, 0, stream>>>(f, m, partials);
        lcc_finalize<<<1, 256, 0, stream>>>(partials, NPART, out);
    } else {
        const int nb = 512;
        float* partials = (float*)d_ws;
        lcc_direct<<<nb, 256, 0, stream>>>(f, m, partials);
        lcc_finalize<<<1, 256, 0, stream>>>(partials, nb, out);
    }
}